// Round 13
// baseline (423.426 us; speedup 1.0000x reference)
//
#include <hip/hip_runtime.h>
#include <hip/hip_fp16.h>
#include <math.h>

// ---------------------------------------------------------------------------
// Multi-layer diffractive optical model (4 layers, 48 images of 512x512 c64).
//   field = x*exp(i*phase*coeff); 4x [prop(H1); phase]; prop(H1*Hf); |field|^2
// FFT: 512-pt radix-8 Stockham, 3 stages, 64 lanes/transform, 8 elems/lane.
// Row pass: barrier-free (wave-private 4KB LDS, lgkmcnt fences) — at HBM peak.
// Col pass (k_colf): column PAIR per thread (16 cols/512-thr block, 64B
//   global segments — 64B is the partial-line write-amp sector, r8 vs r11).
//   FP16 LDS STAGE: mid-FFT exchange values packed half2 (uint2, 8B/elem)
//   -> 32KB stage, halved LDS traffic. Twiddles as running products (no
//   register arrays, same chained-cmul fp sequence). H prefetched packed
//   fp16. launch_bounds(512,3): VGPR cap 85 (cap=256/minW rule; (512,4)'s
//   64-cap spilled ~106 live regs = the r9/r10 "write amplification").
//   waves/SIMD = floor(512/VGPR) -> at <=85 VGPR: 3 blocks/CU (24 waves),
//   vs r11's 2 blocks (64KB f32 stage + 76 VGPR, 42.6us latency-bound).
// CSWZ float4->uint2 stage measured ZERO bank conflicts in r11; fp16-8B
//   keeps reads/stage-1 writes at the 4-lane/bank-pair floor (stage-0
//   writes 2x floor — acceptable). [512][9]-style strides are 8-way
//   conflicted (r12 PMC: 4.7M cycles) — do not use.
// FIELD fp16 interleaved between passes; all math fp32; H tables f32.
// ---------------------------------------------------------------------------

#define TWOPI_F 6.2831854820251465f
#define RSQ2    0.70710678f
#define NPIX    (48*512*512)

__device__ __forceinline__ float2 cadd(float2 a, float2 b){ return make_float2(a.x+b.x, a.y+b.y); }
__device__ __forceinline__ float2 csub(float2 a, float2 b){ return make_float2(a.x-b.x, a.y-b.y); }
__device__ __forceinline__ float2 cmul(float2 a, float2 b){ return make_float2(a.x*b.x - a.y*b.y, a.x*b.y + a.y*b.x); }

template<int S> __device__ __forceinline__ float2 mul_i(float2 a){   // * (S*i)
  return (S>0) ? make_float2(-a.y, a.x) : make_float2(a.y, -a.x);
}
template<int S> __device__ __forceinline__ float2 mul_w1(float2 a){  // * (1 + S*i)/sqrt2
  return (S>0) ? make_float2(RSQ2*(a.x-a.y), RSQ2*(a.x+a.y))
               : make_float2(RSQ2*(a.x+a.y), RSQ2*(a.y-a.x));
}
template<int S> __device__ __forceinline__ float2 mul_w3(float2 a){  // * (-1 + S*i)/sqrt2
  return (S>0) ? make_float2(RSQ2*(-a.x-a.y), RSQ2*(a.x-a.y))
               : make_float2(RSQ2*(a.y-a.x), RSQ2*(-a.x-a.y));
}
// tw stored with FORWARD sign (exp(-i theta)); S=+1 uses conjugate.
template<int S> __device__ __forceinline__ float2 cmul_tw(float2 v, float2 w){
  float wy = (S>0) ? -w.y : w.y;
  return make_float2(v.x*w.x - v.y*wy, v.x*wy + v.y*w.x);
}

// ---- float4 = two independent complex values (column pair), same ops -------
__device__ __forceinline__ float4 f4add(float4 a, float4 b){ return make_float4(a.x+b.x,a.y+b.y,a.z+b.z,a.w+b.w); }
__device__ __forceinline__ float4 f4sub(float4 a, float4 b){ return make_float4(a.x-b.x,a.y-b.y,a.z-b.z,a.w-b.w); }
template<int S> __device__ __forceinline__ float4 mul_i4(float4 a){
  return (S>0) ? make_float4(-a.y,a.x,-a.w,a.z) : make_float4(a.y,-a.x,a.w,-a.z);
}
template<int S> __device__ __forceinline__ float4 mul_w14(float4 a){
  return (S>0) ? make_float4(RSQ2*(a.x-a.y), RSQ2*(a.x+a.y), RSQ2*(a.z-a.w), RSQ2*(a.z+a.w))
               : make_float4(RSQ2*(a.x+a.y), RSQ2*(a.y-a.x), RSQ2*(a.z+a.w), RSQ2*(a.w-a.z));
}
template<int S> __device__ __forceinline__ float4 mul_w34(float4 a){
  return (S>0) ? make_float4(RSQ2*(-a.x-a.y), RSQ2*(a.x-a.y), RSQ2*(-a.z-a.w), RSQ2*(a.z-a.w))
               : make_float4(RSQ2*(a.y-a.x), RSQ2*(-a.x-a.y), RSQ2*(a.w-a.z), RSQ2*(-a.z-a.w));
}
template<int S> __device__ __forceinline__ float4 cmul_tw4(float4 v, float2 w){
  float wy = (S>0) ? -w.y : w.y;
  return make_float4(v.x*w.x - v.y*wy, v.x*wy + v.y*w.x,
                     v.z*w.x - v.w*wy, v.z*wy + v.w*w.x);
}
__device__ __forceinline__ float4 cmulh4(float4 v, float4 h){   // per-column H
  return make_float4(v.x*h.x - v.y*h.y, v.x*h.y + v.y*h.x,
                     v.z*h.z - v.w*h.w, v.z*h.w + v.w*h.z);
}

// fp16 pack/unpack for the col-pass LDS stage and H registers
__device__ __forceinline__ uint2 pk4(float4 v){
  __half2 h0 = __floats2half2_rn(v.x, v.y);
  __half2 h1 = __floats2half2_rn(v.z, v.w);
  uint2 u;
  u.x = *reinterpret_cast<unsigned int*>(&h0);
  u.y = *reinterpret_cast<unsigned int*>(&h1);
  return u;
}
__device__ __forceinline__ float4 upk4(uint2 u){
  __half2 h0, h1;
  *reinterpret_cast<unsigned int*>(&h0) = u.x;
  *reinterpret_cast<unsigned int*>(&h1) = u.y;
  float2 a = __half22float2(h0), b = __half22float2(h1);
  return make_float4(a.x, a.y, b.x, b.y);
}

// 8-point DIF DFT; outputs bit-reversed: A_k = d[km[k]], km = {0,4,2,6,1,5,3,7}
template<int S>
__device__ __forceinline__ void dft8(const float2* a, float2* d){
  float2 b0=cadd(a[0],a[4]), b1=cadd(a[1],a[5]), b2=cadd(a[2],a[6]), b3=cadd(a[3],a[7]);
  float2 b4=csub(a[0],a[4]);
  float2 b5=mul_w1<S>(csub(a[1],a[5]));
  float2 b6=mul_i<S> (csub(a[2],a[6]));
  float2 b7=mul_w3<S>(csub(a[3],a[7]));
  float2 c0=cadd(b0,b2), c2=csub(b0,b2);
  float2 c1=cadd(b1,b3), c3=mul_i<S>(csub(b1,b3));
  float2 c4=cadd(b4,b6), c6=csub(b4,b6);
  float2 c5=cadd(b5,b7), c7=mul_i<S>(csub(b5,b7));
  d[0]=cadd(c0,c1); d[1]=csub(c0,c1);
  d[2]=cadd(c2,c3); d[3]=csub(c2,c3);
  d[4]=cadd(c4,c5); d[5]=csub(c4,c5);
  d[6]=cadd(c6,c7); d[7]=csub(c6,c7);
}
template<int S>
__device__ __forceinline__ void dft8_4(const float4* a, float4* d){
  float4 b0=f4add(a[0],a[4]), b1=f4add(a[1],a[5]), b2=f4add(a[2],a[6]), b3=f4add(a[3],a[7]);
  float4 b4=f4sub(a[0],a[4]);
  float4 b5=mul_w14<S>(f4sub(a[1],a[5]));
  float4 b6=mul_i4<S> (f4sub(a[2],a[6]));
  float4 b7=mul_w34<S>(f4sub(a[3],a[7]));
  float4 c0=f4add(b0,b2), c2=f4sub(b0,b2);
  float4 c1=f4add(b1,b3), c3=mul_i4<S>(f4sub(b1,b3));
  float4 c4=f4add(b4,b6), c6=f4sub(b4,b6);
  float4 c5=f4add(b5,b7), c7=mul_i4<S>(f4sub(b5,b7));
  d[0]=f4add(c0,c1); d[1]=f4sub(c0,c1);
  d[2]=f4add(c2,c3); d[3]=f4sub(c2,c3);
  d[4]=f4add(c4,c5); d[5]=f4sub(c4,c5);
  d[6]=f4add(c6,c7); d[7]=f4sub(c6,c7);
}

// LDS swizzle for stride-1 wave-private buffers: b64 4-lane/bank-pair floor.
__device__ __forceinline__ int SWZR(int i){ return i ^ ((i>>4)&7); }
// Col-pair stage mapping: element e of pair-slot cx -> uint2 index (bank-uniform).
__device__ __forceinline__ int CSWZ(int e, int cx){ return (e<<3) + (cx ^ ((e>>3)&7)); }

// Intra-wave LDS fence.
__device__ __forceinline__ void lds_fence(){ asm volatile("s_waitcnt lgkmcnt(0)" ::: "memory"); }

// Per-thread twiddles (forward sign), computed once per kernel (row kernels).
__device__ __forceinline__ void make_tw(int t, float2* tw0, float2* tw1){
  float sn, cs;
  __sincosf((TWOPI_F/512.0f)*(float)t, &sn, &cs);
  float2 w0 = make_float2(cs, -sn);
  tw0[0] = make_float2(1.0f, 0.0f);
  #pragma unroll
  for(int k=1;k<8;k++) tw0[k] = cmul(tw0[k-1], w0);
  int p = t>>3;
  __sincosf((TWOPI_F/64.0f)*(float)p, &sn, &cs);
  float2 w1 = make_float2(cs, -sn);
  tw1[0] = make_float2(1.0f, 0.0f);
  #pragma unroll
  for(int k=1;k<8;k++) tw1[k] = cmul(tw1[k-1], w1);
}

// 512-pt FFT, wave-private single buffer, stride-1 + SWZR, NO block barriers.
template<int S>
__device__ __forceinline__ void fft512_wv(float2* a, float2* o, float2* B, int t,
                                          float scale, const float2* tw0, const float2* tw1){
  const int km[8] = {0,4,2,6,1,5,3,7};
  float2 d[8];
  dft8<S>(a, d);                                    // stage 0
  #pragma unroll
  for(int k=0;k<8;k++)
    B[SWZR(8*t+k)] = (k==0) ? d[0] : cmul_tw<S>(d[km[k]], tw0[k]);
  lds_fence();
  #pragma unroll
  for(int r=0;r<8;r++) a[r] = B[SWZR(t+64*r)];
  lds_fence();
  dft8<S>(a, d);                                    // stage 1
  {
    int p = t>>3, q = t&7;
    #pragma unroll
    for(int k=0;k<8;k++)
      B[SWZR(q + 64*p + 8*k)] = (k==0) ? d[0] : cmul_tw<S>(d[km[k]], tw1[k]);
  }
  lds_fence();
  #pragma unroll
  for(int r=0;r<8;r++) a[r] = B[SWZR(t+64*r)];
  lds_fence();
  dft8<S>(a, d);                                    // stage 2
  #pragma unroll
  for(int k=0;k<8;k++) o[k] = make_float2(d[km[k]].x*scale, d[km[k]].y*scale);
}

// 512-pt FFT on a COLUMN PAIR, fp16-packed 32KB LDS stage, running twiddles.
// Caller must barrier before reusing B for writes after this returns.
template<int S>
__device__ __forceinline__ void fft512_ph(float4* a, float4* o, uint2* B, int t, int cx,
                                          float scale){
  const int km[8] = {0,4,2,6,1,5,3,7};
  float4 d[8];
  dft8_4<S>(a, d);                                  // stage 0
  {
    float sn, cs; __sincosf((TWOPI_F/512.0f)*(float)t, &sn, &cs);
    float2 w0 = make_float2(cs, -sn);
    float2 tw = make_float2(1.0f, 0.0f);
    #pragma unroll
    for(int k=0;k<8;k++){
      float4 v = (k==0) ? d[0] : cmul_tw4<S>(d[km[k]], tw);
      B[CSWZ(8*t+k, cx)] = pk4(v);
      tw = cmul(tw, w0);
    }
  }
  __syncthreads();
  #pragma unroll
  for(int r=0;r<8;r++) a[r] = upk4(B[CSWZ(t+64*r, cx)]);
  __syncthreads();
  dft8_4<S>(a, d);                                  // stage 1
  {
    int p = t>>3, q = t&7;
    float sn, cs; __sincosf((TWOPI_F/64.0f)*(float)p, &sn, &cs);
    float2 w1 = make_float2(cs, -sn);
    float2 tw = make_float2(1.0f, 0.0f);
    #pragma unroll
    for(int k=0;k<8;k++){
      float4 v = (k==0) ? d[0] : cmul_tw4<S>(d[km[k]], tw);
      B[CSWZ(q + 64*p + 8*k, cx)] = pk4(v);
      tw = cmul(tw, w1);
    }
  }
  __syncthreads();
  #pragma unroll
  for(int r=0;r<8;r++) a[r] = upk4(B[CSWZ(t+64*r, cx)]);
  dft8_4<S>(a, d);                                  // stage 2, regs only
  #pragma unroll
  for(int k=0;k<8;k++)
    o[k] = make_float4(d[km[k]].x*scale, d[km[k]].y*scale, d[km[k]].z*scale, d[km[k]].w*scale);
}

// 512-pt FFT, block-shared single buffer, element stride LD (fallback col kernel).
template<int S, int LD>
__device__ __forceinline__ void fft512_1b(float2* a, float2* o, float2* B, int t,
                                          float scale, const float2* tw0, const float2* tw1){
  const int km[8] = {0,4,2,6,1,5,3,7};
  float2 d[8];
  dft8<S>(a, d);
  #pragma unroll
  for(int k=0;k<8;k++)
    B[(8*t+k)*LD] = (k==0) ? d[0] : cmul_tw<S>(d[km[k]], tw0[k]);
  __syncthreads();
  #pragma unroll
  for(int r=0;r<8;r++) a[r] = B[(t+64*r)*LD];
  __syncthreads();
  dft8<S>(a, d);
  {
    int p = t>>3, q = t&7;
    #pragma unroll
    for(int k=0;k<8;k++)
      B[(q + 64*p + 8*k)*LD] = (k==0) ? d[0] : cmul_tw<S>(d[km[k]], tw1[k]);
  }
  __syncthreads();
  #pragma unroll
  for(int r=0;r<8;r++) a[r] = B[(t+64*r)*LD];
  dft8<S>(a, d);
  #pragma unroll
  for(int k=0;k<8;k++) o[k] = make_float2(d[km[k]].x*scale, d[km[k]].y*scale);
}

// --- Field accessors ---------------------------------------------------------

struct AccH {                            // fp16 interleaved (primary)
  __half2* p;
  __device__ __forceinline__ float2 ld(int i) const { return __half22float2(p[i]); }
  __device__ __forceinline__ void   st(int i, float2 v) const { p[i] = __floats2half2_rn(v.x, v.y); }
};
struct AccS {                            // split f32 planes (fallback)
  float* re; float* im;
  __device__ __forceinline__ float2 ld(int i) const { return make_float2(re[i], im[i]); }
  __device__ __forceinline__ void   st(int i, float2 v) const { re[i]=v.x; im[i]=v.y; }
};

// --- Setup kernel: H1(0.03) and H12 = H(0.03)*H(0.05), f32 ------------------

__device__ __forceinline__ float2 phase_of(float kz, float zf){
  float tt = __fmul_rn(kz, zf);
  double dt = (double)tt;                          // accurate mod-2pi reduction
  double q  = rint(dt * 0.15915494309189535);
  double rr = fma(-q, 6.283185307179586, dt);
  float sn, cs; __sincosf((float)rr, &sn, &cs);
  return make_float2(cs, sn);
}

__global__ __launch_bounds__(256) void k_htab(const float* __restrict__ lams,
                                              float2* __restrict__ H1, float2* __restrict__ H12){
  int e = blockIdx.x*256 + threadIdx.x;            // e < 3*512*512
  int c = e >> 18, fy = (e>>9)&511, col = e&511;
  const float lam = lams[c];
  const float il  = 1.0f / lam;
  const float il2 = __fmul_rn(il, il);
  const float DEN = (float)(512.0 * 8e-6);
  int   sx  = (col < 256) ? col : col - 512;
  int   sy  = (fy  < 256) ? fy  : fy  - 512;
  float fxv = (float)sx / DEN, fyv = (float)sy / DEN;
  float arg = __fsub_rn(il2, __fadd_rn(__fmul_rn(fxv,fxv), __fmul_rn(fyv,fyv)));
  float2 h1 = make_float2(0.0f,0.0f), h12 = h1;
  if(arg > 0.0f){
    float s  = (float)sqrt((double)arg);           // correctly-rounded f32 sqrt
    float kz = __fmul_rn(6.2831854820251465f, s);
    h1  = phase_of(kz, 0.03f);
    h12 = cmul(h1, phase_of(kz, 0.05f));
  }
  H1[e] = h1; H12[e] = h12;
}

// --- Row pass kernels: one wave per row, 4 rows per block, barrier-free ------

template<class Acc>
__global__ __launch_bounds__(256) void k_row_first(
    const float* __restrict__ x, Acc f,
    const float* __restrict__ phases, const float* __restrict__ coeffs)
{
  __shared__ float2 lds[4][512];
  const int w = threadIdx.x >> 6, t = threadIdx.x & 63;
  const int img = blockIdx.x, c = img % 3;
  const int row = (blockIdx.y<<2) + w;
  const int base = (img*512 + row)*512;
  const float* ph = phases + row*512;              // layer 0
  const float coeff = coeffs[c];
  float2 tw0[8], tw1[8]; make_tw(t, tw0, tw1);
  float2 a[8], o[8];
  #pragma unroll
  for(int r=0;r<8;r++){
    int i = t + (r<<6);
    float xv = x[base+i];
    float th = __fmul_rn(ph[i], coeff);
    float sn, cs; __sincosf(th, &sn, &cs);
    a[r] = make_float2(xv*cs, xv*sn);
  }
  fft512_wv<-1>(a, o, lds[w], t, 1.0f, tw0, tw1);
  #pragma unroll
  for(int k=0;k<8;k++){ int i=t+(k<<6); f.st(base+i, o[k]); }
}

template<class Acc>
__global__ __launch_bounds__(256) void k_row_mid(
    Acc f, const float* __restrict__ phases, const float* __restrict__ coeffs, int layer)
{
  __shared__ float2 lds[4][512];
  const int w = threadIdx.x >> 6, t = threadIdx.x & 63;
  const int img = blockIdx.x, c = img % 3;
  const int row = (blockIdx.y<<2) + w;
  const int base = (img*512 + row)*512;
  const float* ph = phases + (layer*512 + row)*512;
  const float coeff = coeffs[layer*3 + c];
  float2 tw0[8], tw1[8]; make_tw(t, tw0, tw1);
  float2 a[8], o[8], pv[8];
  #pragma unroll
  for(int r=0;r<8;r++){
    int i=t+(r<<6); a[r]=f.ld(base+i);
    float th = __fmul_rn(ph[i], coeff);
    float sn, cs; __sincosf(th, &sn, &cs);
    pv[r] = make_float2(cs, sn);
  }
  fft512_wv<+1>(a, o, lds[w], t, 1.0f/512.0f, tw0, tw1);   // row IFFT
  #pragma unroll
  for(int k=0;k<8;k++) a[k] = cmul(o[k], pv[k]);
  fft512_wv<-1>(a, o, lds[w], t, 1.0f, tw0, tw1);          // row FFT
  #pragma unroll
  for(int k=0;k<8;k++){ int i=t+(k<<6); f.st(base+i, o[k]); }
}

template<class Acc>
__global__ __launch_bounds__(256) void k_row_last(
    Acc f, float* __restrict__ out)
{
  __shared__ float2 lds[4][512];
  const int w = threadIdx.x >> 6, t = threadIdx.x & 63;
  const int img = blockIdx.x;
  const int row = (blockIdx.y<<2) + w;
  const int base = (img*512 + row)*512;
  float2 tw0[8], tw1[8]; make_tw(t, tw0, tw1);
  float2 a[8], o[8];
  #pragma unroll
  for(int r=0;r<8;r++){ int i=t+(r<<6); a[r]=f.ld(base+i); }
  fft512_wv<+1>(a, o, lds[w], t, 1.0f/512.0f, tw0, tw1);   // row IFFT
  #pragma unroll
  for(int k=0;k<8;k++){ int i=t+(k<<6); out[base+i] = o[k].x*o[k].x + o[k].y*o[k].y; }
}

// --- Column pass: column-PAIR per thread, fp16 LDS stage (32KB) --------------
// 512 thr = 8 pairs (16 cols) per block; 8B/lane global access = 64B segments.

__global__ __launch_bounds__(512, 3) void k_colf(
    __half2* __restrict__ F, const float2* __restrict__ Htab)
{
  __shared__ uint2 lds[512*8];          // 32 KiB fp16-packed stage, CSWZ layout
  const int cx = threadIdx.x & 7, t = threadIdx.x >> 3;
  const int img = blockIdx.x, c = img % 3;
  const int col = (blockIdx.y<<4) + (cx<<1);       // base column of the pair
  const int ibase = (img<<18) + col;
  float4 a[8], o[8];
  uint2 hp[8];                                     // H prefetched, fp16-packed
  #pragma unroll
  for(int r=0;r<8;r++){
    int gi = ibase + ((t+(r<<6))<<9);
    uint2 raw = *reinterpret_cast<const uint2*>(F + gi);   // two half2 = 8B
    a[r] = upk4(raw);
  }
  #pragma unroll
  for(int k=0;k<8;k++){
    int fy = t + (k<<6);
    float4 hv = *reinterpret_cast<const float4*>(Htab + (c<<18) + (fy<<9) + col); // 16B
    hp[k] = pk4(hv);
  }
  fft512_ph<-1>(a, o, lds, t, cx, 1.0f);           // col FFT (both cols)
  #pragma unroll
  for(int k=0;k<8;k++) a[k] = cmulh4(o[k], upk4(hp[k]));
  __syncthreads();                                  // LDS reuse fence
  fft512_ph<+1>(a, o, lds, t, cx, 1.0f/512.0f);    // col IFFT
  #pragma unroll
  for(int k=0;k<8;k++){
    int gi = ibase + ((t+(k<<6))<<9);
    *reinterpret_cast<uint2*>(F + gi) = pk4(o[k]);
  }
}

// --- Fallback column pass (f32 split planes): 8 cols / 512-thr block ---------

template<class Acc, bool TAB>
__global__ __launch_bounds__(512, 2) void k_col8(
    Acc f, const float2* __restrict__ Htab, const float* __restrict__ lams, float z1, float z2)
{
  __shared__ float2 lds[512][9];        // 36 KiB
  const int cx = threadIdx.x & 7, t = threadIdx.x >> 3;
  const int img = blockIdx.x, c = img % 3;
  const int col = (blockIdx.y<<3) + cx;
  const int ibase = (img<<18) + col;
  float2 tw0[8], tw1[8]; make_tw(t, tw0, tw1);
  float2 a[8], o[8], h[8];
  #pragma unroll
  for(int r=0;r<8;r++){ int gi = ibase + ((t+(r<<6))<<9); a[r]=f.ld(gi); }
  if(TAB){
    const float2* Hrow = Htab + (c<<18) + col;
    #pragma unroll
    for(int k=0;k<8;k++) h[k] = Hrow[(t+(k<<6))<<9];
  } else {
    const float lam = lams[c];
    const float il  = 1.0f / lam;
    const float il2 = __fmul_rn(il, il);
    const float DEN = (float)(512.0 * 8e-6);
    int   sx  = (col < 256) ? col : col - 512;
    float fxv = (float)sx / DEN;
    float fx2 = __fmul_rn(fxv, fxv);
    #pragma unroll
    for(int k=0;k<8;k++){
      int fy = t + (k<<6);
      int sy = (fy < 256) ? fy : fy - 512;
      float fyv = (float)sy / DEN;
      float arg = __fsub_rn(il2, __fadd_rn(fx2, __fmul_rn(fyv,fyv)));
      h[k] = make_float2(0.0f, 0.0f);
      if(arg > 0.0f){
        float s  = (float)sqrt((double)arg);
        float kz = __fmul_rn(6.2831854820251465f, s);
        h[k] = phase_of(kz, z1);
        if(z2 != 0.0f) h[k] = cmul(h[k], phase_of(kz, z2));
      }
    }
  }
  fft512_1b<-1,9>(a, o, &lds[0][cx], t, 1.0f, tw0, tw1);
  #pragma unroll
  for(int k=0;k<8;k++) a[k] = cmul(o[k], h[k]);
  __syncthreads();
  fft512_1b<+1,9>(a, o, &lds[0][cx], t, 1.0f/512.0f, tw0, tw1);
  #pragma unroll
  for(int k=0;k<8;k++){ int gi = ibase + ((t+(k<<6))<<9); f.st(gi, o[k]); }
}

// ---------------------------------------------------------------------------

extern "C" void kernel_launch(void* const* d_in, const int* in_sizes, int n_in,
                              void* d_out, int out_size, void* d_ws, size_t ws_size,
                              hipStream_t stream)
{
  const float* x      = (const float*)d_in[0];
  const float* phases = (const float*)d_in[1];
  const float* coeffs = (const float*)d_in[2];
  const float* lams   = (const float*)d_in[3];
  float* out = (float*)d_out;

  const size_t fldH = (size_t)NPIX*4;              // fp16 interleaved field: 50.3MB
  const size_t splB = (size_t)NPIX*4;              // split f32 im plane:     50.3MB
  const size_t tabB = (size_t)3*512*512*8;         // one H table (f32):       6.3MB

  dim3 gA(48,128), bA(256);
  dim3 gP(48,32),  bP(512);                        // column-pair pass
  dim3 gB(48,64),  bB(512);                        // fallback col pass
  dim3 gH(3*512*512/256), bH(256);

  if(ws_size >= fldH + 2*tabB){
    // --- mode H: fp16 interleaved field + f32 H tables, fp16-stage col pass ---
    AccH f { (__half2*)d_ws };
    float2* H1  = (float2*)((char*)d_ws + fldH);
    float2* H12 = H1 + 3*512*512;
    k_htab<<<gH, bH, 0, stream>>>(lams, H1, H12);
    k_row_first<AccH><<<gA, bA, 0, stream>>>(x, f, phases, coeffs);
    for(int l=1; l<=3; l++){
      k_colf<<<gP, bP, 0, stream>>>((__half2*)d_ws, H1);
      k_row_mid<AccH><<<gA, bA, 0, stream>>>(f, phases, coeffs, l);
    }
    k_colf<<<gP, bP, 0, stream>>>((__half2*)d_ws, H12);
    k_row_last<AccH><<<gA, bA, 0, stream>>>(f, out);
  } else if(ws_size >= splB + 2*tabB){
    // --- mode B: split f32 planes + H tables ---
    AccS f { out, (float*)d_ws };
    float2* H1  = (float2*)((char*)d_ws + splB);
    float2* H12 = H1 + 3*512*512;
    k_htab<<<gH, bH, 0, stream>>>(lams, H1, H12);
    k_row_first<AccS><<<gA, bA, 0, stream>>>(x, f, phases, coeffs);
    for(int l=1; l<=3; l++){
      k_col8<AccS,true><<<gB, bB, 0, stream>>>(f, H1, lams, 0.03f, 0.0f);
      k_row_mid<AccS><<<gA, bA, 0, stream>>>(f, phases, coeffs, l);
    }
    k_col8<AccS,true><<<gB, bB, 0, stream>>>(f, H12, lams, 0.03f, 0.0f);
    k_row_last<AccS><<<gA, bA, 0, stream>>>(f, out);
  } else {
    // --- mode C: split f32 planes, inline H ---
    AccS f { out, (float*)d_ws };
    k_row_first<AccS><<<gA, bA, 0, stream>>>(x, f, phases, coeffs);
    for(int l=1; l<=3; l++){
      k_col8<AccS,false><<<gB, bB, 0, stream>>>(f, nullptr, lams, 0.03f, 0.0f);
      k_row_mid<AccS><<<gA, bA, 0, stream>>>(f, phases, coeffs, l);
    }
    k_col8<AccS,false><<<gB, bB, 0, stream>>>(f, nullptr, lams, 0.03f, 0.05f);
    k_row_last<AccS><<<gA, bA, 0, stream>>>(f, out);
  }
}

// Round 14
// 290.756 us; speedup vs baseline: 1.4563x; 1.4563x over previous
//
#include <hip/hip_runtime.h>
#include <hip/hip_fp16.h>
#include <math.h>

// ---------------------------------------------------------------------------
// Multi-layer diffractive optical model (4 layers, 48 images of 512x512 c64).
//   field = x*exp(i*phase*coeff); 4x [prop(H1); phase]; prop(H1*Hf); |field|^2
// FFT: 512-pt radix-8 Stockham, 3 stages, 64 lanes/transform, 8 elems/lane.
// Row pass: barrier-free (wave-private 4KB LDS, lgkmcnt fences) — at HBM peak.
// Col pass (k_col8): ONE column per thread, 8 cols/512-thr block (r8's best
//   clean config: VGPR 48 < 64 line -> 32-wave ceiling). LDS stage 32KB with
//   swizzle CIDX(e,cx) = ((e^((e>>3)&1))<<3) | (cx^((e>>1)&7)):
//   all three access patterns hit the b64 4-lane/bank-pair floor
//   (r8's [512][9] stride-9 stage was 8-way conflicted on stage-0 writes:
//   4.7M conflict cycles = 19% of wall — THE fix this round).
// Register-budget law (measured r9-r13): VGPR cap = 256/min_waves_arg;
//   pair kernels (live ~106) spill under any cap giving >16 waves — single
//   column float2 (live ~48) is the only shape under the 64-VGPR line.
// FIELD fp16 interleaved between passes; all math fp32; H tables f32.
// ---------------------------------------------------------------------------

#define TWOPI_F 6.2831854820251465f
#define RSQ2    0.70710678f
#define NPIX    (48*512*512)

__device__ __forceinline__ float2 cadd(float2 a, float2 b){ return make_float2(a.x+b.x, a.y+b.y); }
__device__ __forceinline__ float2 csub(float2 a, float2 b){ return make_float2(a.x-b.x, a.y-b.y); }
__device__ __forceinline__ float2 cmul(float2 a, float2 b){ return make_float2(a.x*b.x - a.y*b.y, a.x*b.y + a.y*b.x); }

template<int S> __device__ __forceinline__ float2 mul_i(float2 a){   // * (S*i)
  return (S>0) ? make_float2(-a.y, a.x) : make_float2(a.y, -a.x);
}
template<int S> __device__ __forceinline__ float2 mul_w1(float2 a){  // * (1 + S*i)/sqrt2
  return (S>0) ? make_float2(RSQ2*(a.x-a.y), RSQ2*(a.x+a.y))
               : make_float2(RSQ2*(a.x+a.y), RSQ2*(a.y-a.x));
}
template<int S> __device__ __forceinline__ float2 mul_w3(float2 a){  // * (-1 + S*i)/sqrt2
  return (S>0) ? make_float2(RSQ2*(-a.x-a.y), RSQ2*(a.x-a.y))
               : make_float2(RSQ2*(a.y-a.x), RSQ2*(-a.x-a.y));
}
// tw stored with FORWARD sign (exp(-i theta)); S=+1 uses conjugate.
template<int S> __device__ __forceinline__ float2 cmul_tw(float2 v, float2 w){
  float wy = (S>0) ? -w.y : w.y;
  return make_float2(v.x*w.x - v.y*wy, v.x*wy + v.y*w.x);
}

// 8-point DIF DFT; outputs bit-reversed: A_k = d[km[k]], km = {0,4,2,6,1,5,3,7}
template<int S>
__device__ __forceinline__ void dft8(const float2* a, float2* d){
  float2 b0=cadd(a[0],a[4]), b1=cadd(a[1],a[5]), b2=cadd(a[2],a[6]), b3=cadd(a[3],a[7]);
  float2 b4=csub(a[0],a[4]);
  float2 b5=mul_w1<S>(csub(a[1],a[5]));
  float2 b6=mul_i<S> (csub(a[2],a[6]));
  float2 b7=mul_w3<S>(csub(a[3],a[7]));
  float2 c0=cadd(b0,b2), c2=csub(b0,b2);
  float2 c1=cadd(b1,b3), c3=mul_i<S>(csub(b1,b3));
  float2 c4=cadd(b4,b6), c6=csub(b4,b6);
  float2 c5=cadd(b5,b7), c7=mul_i<S>(csub(b5,b7));
  d[0]=cadd(c0,c1); d[1]=csub(c0,c1);
  d[2]=cadd(c2,c3); d[3]=csub(c2,c3);
  d[4]=cadd(c4,c5); d[5]=csub(c4,c5);
  d[6]=cadd(c6,c7); d[7]=csub(c6,c7);
}

// LDS swizzle for stride-1 wave-private buffers: b64 4-lane/bank-pair floor.
__device__ __forceinline__ int SWZR(int i){ return i ^ ((i>>4)&7); }
// Col stage swizzle: bijective; all three FFT access patterns hit the b64
// 4-lane/bank-pair floor (halfbit = (e&1)^((e>>3)&1), low bits cx^((e>>1)&7)).
__device__ __forceinline__ int CIDX(int e, int cx){
  return ((e ^ ((e>>3)&1))<<3) | (cx ^ ((e>>1)&7));
}

// Intra-wave LDS fence.
__device__ __forceinline__ void lds_fence(){ asm volatile("s_waitcnt lgkmcnt(0)" ::: "memory"); }

// Per-thread twiddles (forward sign), computed once per kernel.
__device__ __forceinline__ void make_tw(int t, float2* tw0, float2* tw1){
  float sn, cs;
  __sincosf((TWOPI_F/512.0f)*(float)t, &sn, &cs);
  float2 w0 = make_float2(cs, -sn);
  tw0[0] = make_float2(1.0f, 0.0f);
  #pragma unroll
  for(int k=1;k<8;k++) tw0[k] = cmul(tw0[k-1], w0);
  int p = t>>3;
  __sincosf((TWOPI_F/64.0f)*(float)p, &sn, &cs);
  float2 w1 = make_float2(cs, -sn);
  tw1[0] = make_float2(1.0f, 0.0f);
  #pragma unroll
  for(int k=1;k<8;k++) tw1[k] = cmul(tw1[k-1], w1);
}

// 512-pt FFT, wave-private single buffer, stride-1 + SWZR, NO block barriers.
template<int S>
__device__ __forceinline__ void fft512_wv(float2* a, float2* o, float2* B, int t,
                                          float scale, const float2* tw0, const float2* tw1){
  const int km[8] = {0,4,2,6,1,5,3,7};
  float2 d[8];
  dft8<S>(a, d);                                    // stage 0
  #pragma unroll
  for(int k=0;k<8;k++)
    B[SWZR(8*t+k)] = (k==0) ? d[0] : cmul_tw<S>(d[km[k]], tw0[k]);
  lds_fence();
  #pragma unroll
  for(int r=0;r<8;r++) a[r] = B[SWZR(t+64*r)];
  lds_fence();
  dft8<S>(a, d);                                    // stage 1
  {
    int p = t>>3, q = t&7;
    #pragma unroll
    for(int k=0;k<8;k++)
      B[SWZR(q + 64*p + 8*k)] = (k==0) ? d[0] : cmul_tw<S>(d[km[k]], tw1[k]);
  }
  lds_fence();
  #pragma unroll
  for(int r=0;r<8;r++) a[r] = B[SWZR(t+64*r)];
  lds_fence();
  dft8<S>(a, d);                                    // stage 2
  #pragma unroll
  for(int k=0;k<8;k++) o[k] = make_float2(d[km[k]].x*scale, d[km[k]].y*scale);
}

// 512-pt FFT, block-shared single buffer, CIDX swizzle (col kernel).
// Caller must barrier before reusing B for writes after this returns.
template<int S>
__device__ __forceinline__ void fft512_cs(float2* a, float2* o, float2* B, int t, int cx,
                                          float scale, const float2* tw0, const float2* tw1){
  const int km[8] = {0,4,2,6,1,5,3,7};
  float2 d[8];
  dft8<S>(a, d);                                    // stage 0
  #pragma unroll
  for(int k=0;k<8;k++)
    B[CIDX(8*t+k, cx)] = (k==0) ? d[0] : cmul_tw<S>(d[km[k]], tw0[k]);
  __syncthreads();
  #pragma unroll
  for(int r=0;r<8;r++) a[r] = B[CIDX(t+64*r, cx)];
  __syncthreads();
  dft8<S>(a, d);                                    // stage 1
  {
    int p = t>>3, q = t&7;
    #pragma unroll
    for(int k=0;k<8;k++)
      B[CIDX(q + 64*p + 8*k, cx)] = (k==0) ? d[0] : cmul_tw<S>(d[km[k]], tw1[k]);
  }
  __syncthreads();
  #pragma unroll
  for(int r=0;r<8;r++) a[r] = B[CIDX(t+64*r, cx)];
  dft8<S>(a, d);                                    // stage 2, regs only
  #pragma unroll
  for(int k=0;k<8;k++) o[k] = make_float2(d[km[k]].x*scale, d[km[k]].y*scale);
}

// --- Field accessors ---------------------------------------------------------

struct AccH {                            // fp16 interleaved (primary)
  __half2* p;
  __device__ __forceinline__ float2 ld(int i) const { return __half22float2(p[i]); }
  __device__ __forceinline__ void   st(int i, float2 v) const { p[i] = __floats2half2_rn(v.x, v.y); }
};
struct AccS {                            // split f32 planes (fallback)
  float* re; float* im;
  __device__ __forceinline__ float2 ld(int i) const { return make_float2(re[i], im[i]); }
  __device__ __forceinline__ void   st(int i, float2 v) const { re[i]=v.x; im[i]=v.y; }
};

// --- Setup kernel: H1(0.03) and H12 = H(0.03)*H(0.05), f32 ------------------

__device__ __forceinline__ float2 phase_of(float kz, float zf){
  float tt = __fmul_rn(kz, zf);
  double dt = (double)tt;                          // accurate mod-2pi reduction
  double q  = rint(dt * 0.15915494309189535);
  double rr = fma(-q, 6.283185307179586, dt);
  float sn, cs; __sincosf((float)rr, &sn, &cs);
  return make_float2(cs, sn);
}

__global__ __launch_bounds__(256) void k_htab(const float* __restrict__ lams,
                                              float2* __restrict__ H1, float2* __restrict__ H12){
  int e = blockIdx.x*256 + threadIdx.x;            // e < 3*512*512
  int c = e >> 18, fy = (e>>9)&511, col = e&511;
  const float lam = lams[c];
  const float il  = 1.0f / lam;
  const float il2 = __fmul_rn(il, il);
  const float DEN = (float)(512.0 * 8e-6);
  int   sx  = (col < 256) ? col : col - 512;
  int   sy  = (fy  < 256) ? fy  : fy  - 512;
  float fxv = (float)sx / DEN, fyv = (float)sy / DEN;
  float arg = __fsub_rn(il2, __fadd_rn(__fmul_rn(fxv,fxv), __fmul_rn(fyv,fyv)));
  float2 h1 = make_float2(0.0f,0.0f), h12 = h1;
  if(arg > 0.0f){
    float s  = (float)sqrt((double)arg);           // correctly-rounded f32 sqrt
    float kz = __fmul_rn(6.2831854820251465f, s);
    h1  = phase_of(kz, 0.03f);
    h12 = cmul(h1, phase_of(kz, 0.05f));
  }
  H1[e] = h1; H12[e] = h12;
}

// --- Row pass kernels: one wave per row, 4 rows per block, barrier-free ------

template<class Acc>
__global__ __launch_bounds__(256) void k_row_first(
    const float* __restrict__ x, Acc f,
    const float* __restrict__ phases, const float* __restrict__ coeffs)
{
  __shared__ float2 lds[4][512];
  const int w = threadIdx.x >> 6, t = threadIdx.x & 63;
  const int img = blockIdx.x, c = img % 3;
  const int row = (blockIdx.y<<2) + w;
  const int base = (img*512 + row)*512;
  const float* ph = phases + row*512;              // layer 0
  const float coeff = coeffs[c];
  float2 tw0[8], tw1[8]; make_tw(t, tw0, tw1);
  float2 a[8], o[8];
  #pragma unroll
  for(int r=0;r<8;r++){
    int i = t + (r<<6);
    float xv = x[base+i];
    float th = __fmul_rn(ph[i], coeff);
    float sn, cs; __sincosf(th, &sn, &cs);
    a[r] = make_float2(xv*cs, xv*sn);
  }
  fft512_wv<-1>(a, o, lds[w], t, 1.0f, tw0, tw1);
  #pragma unroll
  for(int k=0;k<8;k++){ int i=t+(k<<6); f.st(base+i, o[k]); }
}

template<class Acc>
__global__ __launch_bounds__(256) void k_row_mid(
    Acc f, const float* __restrict__ phases, const float* __restrict__ coeffs, int layer)
{
  __shared__ float2 lds[4][512];
  const int w = threadIdx.x >> 6, t = threadIdx.x & 63;
  const int img = blockIdx.x, c = img % 3;
  const int row = (blockIdx.y<<2) + w;
  const int base = (img*512 + row)*512;
  const float* ph = phases + (layer*512 + row)*512;
  const float coeff = coeffs[layer*3 + c];
  float2 tw0[8], tw1[8]; make_tw(t, tw0, tw1);
  float2 a[8], o[8], pv[8];
  #pragma unroll
  for(int r=0;r<8;r++){
    int i=t+(r<<6); a[r]=f.ld(base+i);
    float th = __fmul_rn(ph[i], coeff);
    float sn, cs; __sincosf(th, &sn, &cs);
    pv[r] = make_float2(cs, sn);
  }
  fft512_wv<+1>(a, o, lds[w], t, 1.0f/512.0f, tw0, tw1);   // row IFFT
  #pragma unroll
  for(int k=0;k<8;k++) a[k] = cmul(o[k], pv[k]);
  fft512_wv<-1>(a, o, lds[w], t, 1.0f, tw0, tw1);          // row FFT
  #pragma unroll
  for(int k=0;k<8;k++){ int i=t+(k<<6); f.st(base+i, o[k]); }
}

template<class Acc>
__global__ __launch_bounds__(256) void k_row_last(
    Acc f, float* __restrict__ out)
{
  __shared__ float2 lds[4][512];
  const int w = threadIdx.x >> 6, t = threadIdx.x & 63;
  const int img = blockIdx.x;
  const int row = (blockIdx.y<<2) + w;
  const int base = (img*512 + row)*512;
  float2 tw0[8], tw1[8]; make_tw(t, tw0, tw1);
  float2 a[8], o[8];
  #pragma unroll
  for(int r=0;r<8;r++){ int i=t+(r<<6); a[r]=f.ld(base+i); }
  fft512_wv<+1>(a, o, lds[w], t, 1.0f/512.0f, tw0, tw1);   // row IFFT
  #pragma unroll
  for(int k=0;k<8;k++){ int i=t+(k<<6); out[base+i] = o[k].x*o[k].x + o[k].y*o[k].y; }
}

// --- Column pass: colFFT -> xH -> colIFFT; 8 cols / 512-thread block ---------
// Single col per thread (VGPR ~48 < 64-line -> 32-wave ceiling); 32KB CIDX stage.

template<class Acc, bool TAB>
__global__ __launch_bounds__(512, 4) void k_col8(
    Acc f, const float2* __restrict__ Htab, const float* __restrict__ lams, float z1, float z2)
{
  __shared__ float2 lds[512*8];         // 32 KiB, CIDX swizzled
  const int cx = threadIdx.x & 7, t = threadIdx.x >> 3;
  const int img = blockIdx.x, c = img % 3;
  const int col = (blockIdx.y<<3) + cx;
  const int ibase = (img<<18) + col;
  float2 tw0[8], tw1[8]; make_tw(t, tw0, tw1);
  float2 a[8], o[8], h[8];
  #pragma unroll
  for(int r=0;r<8;r++){ int gi = ibase + ((t+(r<<6))<<9); a[r]=f.ld(gi); }
  if(TAB){
    const float2* Hrow = Htab + (c<<18) + col;     // prefetch H (independent of FFT)
    #pragma unroll
    for(int k=0;k<8;k++) h[k] = Hrow[(t+(k<<6))<<9];
  } else {
    const float lam = lams[c];
    const float il  = 1.0f / lam;
    const float il2 = __fmul_rn(il, il);
    const float DEN = (float)(512.0 * 8e-6);
    int   sx  = (col < 256) ? col : col - 512;
    float fxv = (float)sx / DEN;
    float fx2 = __fmul_rn(fxv, fxv);
    #pragma unroll
    for(int k=0;k<8;k++){
      int fy = t + (k<<6);
      int sy = (fy < 256) ? fy : fy - 512;
      float fyv = (float)sy / DEN;
      float arg = __fsub_rn(il2, __fadd_rn(fx2, __fmul_rn(fyv,fyv)));
      h[k] = make_float2(0.0f, 0.0f);
      if(arg > 0.0f){
        float s  = (float)sqrt((double)arg);
        float kz = __fmul_rn(6.2831854820251465f, s);
        h[k] = phase_of(kz, z1);
        if(z2 != 0.0f) h[k] = cmul(h[k], phase_of(kz, z2));
      }
    }
  }
  fft512_cs<-1>(a, o, lds, t, cx, 1.0f, tw0, tw1);          // col FFT
  #pragma unroll
  for(int k=0;k<8;k++) a[k] = cmul(o[k], h[k]);
  __syncthreads();                                           // LDS reuse fence
  fft512_cs<+1>(a, o, lds, t, cx, 1.0f/512.0f, tw0, tw1);   // col IFFT
  #pragma unroll
  for(int k=0;k<8;k++){ int gi = ibase + ((t+(k<<6))<<9); f.st(gi, o[k]); }
}

// ---------------------------------------------------------------------------

extern "C" void kernel_launch(void* const* d_in, const int* in_sizes, int n_in,
                              void* d_out, int out_size, void* d_ws, size_t ws_size,
                              hipStream_t stream)
{
  const float* x      = (const float*)d_in[0];
  const float* phases = (const float*)d_in[1];
  const float* coeffs = (const float*)d_in[2];
  const float* lams   = (const float*)d_in[3];
  float* out = (float*)d_out;

  const size_t fldH = (size_t)NPIX*4;              // fp16 interleaved field: 50.3MB
  const size_t splB = (size_t)NPIX*4;              // split f32 im plane:     50.3MB
  const size_t tabB = (size_t)3*512*512*8;         // one H table (f32):       6.3MB

  dim3 gA(48,128), bA(256);
  dim3 gB(48,64),  bB(512);                        // col pass
  dim3 gH(3*512*512/256), bH(256);

  if(ws_size >= fldH + 2*tabB){
    // --- mode H: fp16 interleaved field + f32 H tables ---
    AccH f { (__half2*)d_ws };
    float2* H1  = (float2*)((char*)d_ws + fldH);
    float2* H12 = H1 + 3*512*512;
    k_htab<<<gH, bH, 0, stream>>>(lams, H1, H12);
    k_row_first<AccH><<<gA, bA, 0, stream>>>(x, f, phases, coeffs);
    for(int l=1; l<=3; l++){
      k_col8<AccH,true><<<gB, bB, 0, stream>>>(f, H1, lams, 0.03f, 0.0f);
      k_row_mid<AccH><<<gA, bA, 0, stream>>>(f, phases, coeffs, l);
    }
    k_col8<AccH,true><<<gB, bB, 0, stream>>>(f, H12, lams, 0.03f, 0.0f);
    k_row_last<AccH><<<gA, bA, 0, stream>>>(f, out);
  } else if(ws_size >= splB + 2*tabB){
    // --- mode B: split f32 planes + H tables ---
    AccS f { out, (float*)d_ws };
    float2* H1  = (float2*)((char*)d_ws + splB);
    float2* H12 = H1 + 3*512*512;
    k_htab<<<gH, bH, 0, stream>>>(lams, H1, H12);
    k_row_first<AccS><<<gA, bA, 0, stream>>>(x, f, phases, coeffs);
    for(int l=1; l<=3; l++){
      k_col8<AccS,true><<<gB, bB, 0, stream>>>(f, H1, lams, 0.03f, 0.0f);
      k_row_mid<AccS><<<gA, bA, 0, stream>>>(f, phases, coeffs, l);
    }
    k_col8<AccS,true><<<gB, bB, 0, stream>>>(f, H12, lams, 0.03f, 0.0f);
    k_row_last<AccS><<<gA, bA, 0, stream>>>(f, out);
  } else {
    // --- mode C: split f32 planes, inline H ---
    AccS f { out, (float*)d_ws };
    k_row_first<AccS><<<gA, bA, 0, stream>>>(x, f, phases, coeffs);
    for(int l=1; l<=3; l++){
      k_col8<AccS,false><<<gB, bB, 0, stream>>>(f, nullptr, lams, 0.03f, 0.0f);
      k_row_mid<AccS><<<gA, bA, 0, stream>>>(f, phases, coeffs, l);
    }
    k_col8<AccS,false><<<gB, bB, 0, stream>>>(f, nullptr, lams, 0.03f, 0.05f);
    k_row_last<AccS><<<gA, bA, 0, stream>>>(f, out);
  }
}